// Round 10
// baseline (108.333 us; speedup 1.0000x reference)
//
#include <hip/hip_runtime.h>
#include <hip/hip_bf16.h>
#include <math.h>
#include <string.h>

typedef __attribute__((ext_vector_type(8))) short bf16x8;
typedef __attribute__((ext_vector_type(4))) float f32x4;
typedef __attribute__((ext_vector_type(4))) unsigned int u32x4;

#define BLK 256

// ws layout:
//   [0, 8192)      : W1 Phase-A MFMA fragments, 8 nt-tiles x 64 lanes x 8 bf16.
//                    Lane (n=l&15, q=l>>4), K-slot j within quad:
//                      q0: {W1h[n][0..4], b1h[n], 0, 0}
//                      q1: {W1l[n][0..4], b1l[n], 0, 0}   (lo residuals)
//                      q2: {W1h[n][0..4], 0, 0, 0}        (for xl side)
//                      q3: zeros
//   [8192, 24576)  : W21/W22 GEMM2 fragments with sigma-permuted K:
//                    frag F = mat*8 + nt2*4 + kt; ushort idx F*512 + l*8 + j;
//                    value = W[n2 = nt2*16 + (l&15)][sigma(kt, l>>4, j)]
//                    sigma(kt,q,j) = 16*(2*kt + (j>>2)) + 4*q + (j&3)
//
// R10 = R9 with ONE variable changed: grid 512 (8 iters) instead of 1024 (4).
// Controlled occupancy cut (2 blocks/CU vs 3) to (a) discriminate
// latency-bound vs CU-throughput-bound vs spill, (b) push kernel duration
// above the 43us harness fills so rocprof top-5 shows its counters.

__device__ __forceinline__ unsigned int rne_bf16_bits(float w) {
    unsigned int u = __builtin_bit_cast(unsigned int, w);
    u += 0x7fffu + ((u >> 16) & 1u);
    return u >> 16;
}
__device__ __forceinline__ float bf16_to_f32(unsigned int bits) {
    return __builtin_bit_cast(float, bits << 16);
}
__device__ __forceinline__ unsigned int pk_bf16(float lo, float hi) {
    __hip_bfloat162 bp = __float22bfloat162_rn(make_float2(lo, hi));
    unsigned int r; memcpy(&r, &bp, 4);
    return r;                                     // lo -> low 16, hi -> high 16
}

__global__ void setup_kernel(const float* __restrict__ W1, const float* __restrict__ b1,
                             const float* __restrict__ W21, const float* __restrict__ W22,
                             unsigned short* __restrict__ w1f, unsigned short* __restrict__ frg)
{
    int t = blockIdx.x * blockDim.x + threadIdx.x;   // 0..4095
    {   // W1 Phase-A fragment table (4096 ushorts)
        int e = t;
        int nt = e >> 9, l = (e >> 3) & 63, j = e & 7;
        int n = nt * 16 + (l & 15), q = l >> 4;
        unsigned short v = 0;
        if (q == 0) {
            if (j < 5)       v = (unsigned short)rne_bf16_bits(W1[n * 5 + j]);
            else if (j == 5) v = (unsigned short)rne_bf16_bits(b1[n]);
        } else if (q == 1) {
            if (j < 5) {
                unsigned int h = rne_bf16_bits(W1[n * 5 + j]);
                v = (unsigned short)rne_bf16_bits(W1[n * 5 + j] - bf16_to_f32(h));
            } else if (j == 5) {
                unsigned int h = rne_bf16_bits(b1[n]);
                v = (unsigned short)rne_bf16_bits(b1[n] - bf16_to_f32(h));
            }
        } else if (q == 2) {
            if (j < 5)       v = (unsigned short)rne_bf16_bits(W1[n * 5 + j]);
        }
        w1f[e] = v;
    }
    for (int e = t; e < 16 * 64 * 8; e += 4096) {    // GEMM2 table (8192 ushorts)
        int F = e >> 9, l = (e >> 3) & 63, j = e & 7;
        int mat = F >> 3, nt2 = (F >> 2) & 1, kt = F & 3;
        int n2 = nt2 * 16 + (l & 15), q = l >> 4;
        int ks = 16 * (2 * kt + (j >> 2)) + 4 * q + (j & 3);
        const float* W = mat ? W22 : W21;
        frg[e] = (unsigned short)rne_bf16_bits(W[n2 * 128 + ks]);
    }
}

// 512 blocks (2/CU at 12-wave cap), block = 4 waves = 1024 rows.
// Wave: 8 iters x 32 rows (2 tiles, register-blocked).
__global__ __launch_bounds__(BLK, 3) void barriernet_kernel(
    const float* __restrict__ x,
    const float* __restrict__ mean, const float* __restrict__ stdv,
    const float* __restrict__ b21, const float* __restrict__ b22,
    const float* __restrict__ W31, const float* __restrict__ b31,
    const float* __restrict__ W32, const float* __restrict__ b32,
    const u32x4* __restrict__ w1fg, const u32x4* __restrict__ frg,
    float* __restrict__ out, int zero)
{
    __shared__ u32x4 ldsF[1024];    // 16 GEMM2 frags x 64 lanes

    const int tid = threadIdx.x;
    #pragma unroll
    for (int i = 0; i < 4; ++i) ldsF[tid + i * BLK] = frg[tid + i * BLK];

    const int lane = tid & 63;
    const int wave = tid >> 6;
    const int m    = lane & 15;
    const int q    = lane >> 4;

    // W1 Phase-A fragments: deliberately register-resident (32 VGPRs).
    u32x4 w1f[8];
    #pragma unroll
    for (int nt = 0; nt < 8; ++nt) w1f[nt] = w1fg[nt * 64 + lane];

    // Bias/head vectors: loop-invariant, register-resident (32 VGPRs).
    f32x4 bac[4], whv[4];
    bac[0] = *(const f32x4*)(b21 + q * 4);
    bac[1] = *(const f32x4*)(b21 + 16 + q * 4);
    bac[2] = *(const f32x4*)(b22 + q * 4);
    bac[3] = *(const f32x4*)(b22 + 16 + q * 4);
    whv[0] = *(const f32x4*)(W31 + q * 4);
    whv[1] = *(const f32x4*)(W31 + 16 + q * 4);
    whv[2] = *(const f32x4*)(W32 + q * 4);
    whv[3] = *(const f32x4*)(W32 + 16 + q * 4);

    float sm_s[5], sm_m[5];
    #pragma unroll
    for (int f = 0; f < 5; ++f) { sm_s[f] = stdv[f]; sm_m[f] = mean[f]; }
    const float b31s = b31[0], b32s = b32[0];

    __syncthreads();

    const size_t wrow0 = (size_t)blockIdx.x * 1024 + wave * 256;

    // x prefetch (both tiles of iter 0)
    float4 xc4[2]; float xc1[2];
    #pragma unroll
    for (int T = 0; T < 2; ++T) {
        const float* p = x + (wrow0 + T * 16 + m) * 5;
        xc4[T] = *(const float4*)p; xc1[T] = p[4];
    }

    #pragma unroll 1
    for (int it = 0; it < 8; ++it) {
        // ---- prefetch next iter's x ----
        const int itn = (it < 7) ? it + 1 : 7;
        float4 xn4[2]; float xn1[2];
        #pragma unroll
        for (int T = 0; T < 2; ++T) {
            const float* pn = x + (wrow0 + itn * 32 + T * 16 + m) * 5;
            xn4[T] = *(const float4*)pn; xn1[T] = pn[4];
        }

        float xf[2][5];
        #pragma unroll
        for (int T = 0; T < 2; ++T) {
            xf[T][0] = xc4[T].x; xf[T][1] = xc4[T].y; xf[T][2] = xc4[T].z;
            xf[T][3] = xc4[T].w; xf[T][4] = xc1[T];
        }

        // ---- Phase A per tile: x B-fragment (hi/lo) + 8 MFMAs + pack ----
        unsigned int au[2][4][4];
        #pragma unroll
        for (int T = 0; T < 2; ++T) {
            unsigned int hb[5], lb[5];
            #pragma unroll
            for (int f = 0; f < 5; ++f) {
                hb[f] = rne_bf16_bits(xf[T][f]);
                lb[f] = rne_bf16_bits(xf[T][f] - bf16_to_f32(hb[f]));
            }
            const unsigned int xh01 = hb[0] | (hb[1] << 16);
            const unsigned int xh23 = hb[2] | (hb[3] << 16);
            const unsigned int xh4b = hb[4] | (0x3F80u << 16);   // (xh4, 1.0)
            const unsigned int xl01 = lb[0] | (lb[1] << 16);
            const unsigned int xl23 = lb[2] | (lb[3] << 16);
            const unsigned int xl4  = lb[4];
            const bool ql2 = (q < 2), q2 = (q == 2);
            u32x4 xd;
            xd[0] = ql2 ? xh01 : (q2 ? xl01 : 0u);
            xd[1] = ql2 ? xh23 : (q2 ? xl23 : 0u);
            xd[2] = ql2 ? xh4b : (q2 ? xl4  : 0u);
            xd[3] = 0u;
            const bf16x8 xb = __builtin_bit_cast(bf16x8, xd);

            #pragma unroll
            for (int kt = 0; kt < 4; ++kt) {
                f32x4 z = { 0.0f, 0.0f, 0.0f, 0.0f };
                f32x4 d0 = __builtin_amdgcn_mfma_f32_16x16x32_bf16(
                    __builtin_bit_cast(bf16x8, w1f[2 * kt]),     xb, z, 0, 0, 0);
                f32x4 d1 = __builtin_amdgcn_mfma_f32_16x16x32_bf16(
                    __builtin_bit_cast(bf16x8, w1f[2 * kt + 1]), xb, z, 0, 0, 0);
                au[T][kt][0] = pk_bf16(fmaxf(d0[0], 0.0f), fmaxf(d0[1], 0.0f));
                au[T][kt][1] = pk_bf16(fmaxf(d0[2], 0.0f), fmaxf(d0[3], 0.0f));
                au[T][kt][2] = pk_bf16(fmaxf(d1[0], 0.0f), fmaxf(d1[1], 0.0f));
                au[T][kt][3] = pk_bf16(fmaxf(d1[2], 0.0f), fmaxf(d1[3], 0.0f));
            }
        }

        // ---- GEMM2: 32 MFMAs, each LDS fragment read feeds 2 (anti-hoisted) ----
        f32x4 acc[2][4];
        #pragma unroll
        for (int T = 0; T < 2; ++T)
            #pragma unroll
            for (int c = 0; c < 4; ++c) acc[T][c] = bac[c];
        const int fz = it * zero;
        #pragma unroll
        for (int kt = 0; kt < 4; ++kt) {
            bf16x8 bw[4];
            #pragma unroll
            for (int c = 0; c < 4; ++c) {          // c = mat*2 + nt2
                const int F = (c >> 1) * 8 + (c & 1) * 4 + kt;
                bw[c] = __builtin_bit_cast(bf16x8, ldsF[F * 64 + lane + fz]);
            }
            #pragma unroll
            for (int T = 0; T < 2; ++T) {
                u32x4 t4 = { au[T][kt][0], au[T][kt][1], au[T][kt][2], au[T][kt][3] };
                const bf16x8 a = __builtin_bit_cast(bf16x8, t4);
                #pragma unroll
                for (int c = 0; c < 4; ++c)
                    acc[T][c] = __builtin_amdgcn_mfma_f32_16x16x32_bf16(bw[c], a, acc[T][c], 0, 0, 0);
            }
        }

        // ---- Heads + epilogue per tile ----
        #pragma unroll
        for (int T = 0; T < 2; ++T) {
            float s31 = 0.0f, s32 = 0.0f;
            #pragma unroll
            for (int r = 0; r < 4; ++r) {
                s31 = fmaf(fmaxf(acc[T][0][r], 0.0f), whv[0][r], s31);
                s31 = fmaf(fmaxf(acc[T][1][r], 0.0f), whv[1][r], s31);
                s32 = fmaf(fmaxf(acc[T][2][r], 0.0f), whv[2][r], s32);
                s32 = fmaf(fmaxf(acc[T][3][r], 0.0f), whv[3][r], s32);
            }
            s31 += __shfl_xor(s31, 16);
            s31 += __shfl_xor(s31, 32);
            s32 += __shfl_xor(s32, 16);
            s32 += __shfl_xor(s32, 32);

            const float x31 = s31 + b31s;
            const float z   = s32 + b32s;
            const float x32 = 4.0f / (1.0f + __expf(-z));
            float x0[5];
            #pragma unroll
            for (int f = 0; f < 5; ++f) x0[f] = fmaf(xf[T][f], sm_s[f], sm_m[f]);
            const float h_ineq = (x0[1] - x0[3]) + x32 * (x0[0] - x0[2] - 1.8f * x0[3]);
            const float u_unc  = -x31;
            const float u      = (1.8f * u_unc <= h_ineq) ? u_unc : (h_ineq / 1.8f);
            if (lane < 16)
                out[wrow0 + it * 32 + T * 16 + lane] = u;
        }

        #pragma unroll
        for (int T = 0; T < 2; ++T) { xc4[T] = xn4[T]; xc1[T] = xn1[T]; }
    }
}

extern "C" void kernel_launch(void* const* d_in, const int* in_sizes, int n_in,
                              void* d_out, int out_size, void* d_ws, size_t ws_size,
                              hipStream_t stream) {
    const float* x    = (const float*)d_in[0];
    const float* mean = (const float*)d_in[1];
    const float* stdv = (const float*)d_in[2];
    const float* W1   = (const float*)d_in[3];
    const float* b1   = (const float*)d_in[4];
    const float* W21  = (const float*)d_in[5];
    const float* b21  = (const float*)d_in[6];
    const float* W22  = (const float*)d_in[7];
    const float* b22  = (const float*)d_in[8];
    const float* W31  = (const float*)d_in[9];
    const float* b31  = (const float*)d_in[10];
    const float* W32  = (const float*)d_in[11];
    const float* b32  = (const float*)d_in[12];
    float* out = (float*)d_out;

    unsigned short* w1f = (unsigned short*)d_ws;
    unsigned short* frg = (unsigned short*)((char*)d_ws + 8192);

    setup_kernel<<<16, 256, 0, stream>>>(W1, b1, W21, W22, w1f, frg);

    // 524288 rows / 1024 rows-per-block = 512 blocks (2/CU resident)
    barriernet_kernel<<<512, BLK, 0, stream>>>(
        x, mean, stdv, b21, b22, W31, b31, W32, b32,
        (const u32x4*)w1f, (const u32x4*)frg, out, /*zero=*/0);
}

// Round 11
// 103.937 us; speedup vs baseline: 1.0423x; 1.0423x over previous
//
#include <hip/hip_runtime.h>
#include <hip/hip_bf16.h>
#include <math.h>
#include <string.h>

typedef __attribute__((ext_vector_type(8))) short bf16x8;
typedef __attribute__((ext_vector_type(4))) float f32x4;
typedef __attribute__((ext_vector_type(16))) float f32x16;
typedef __attribute__((ext_vector_type(4))) unsigned int u32x4;

#define BLK 256

// All-32x32x16 pipeline. Batch rows in lane&31 everywhere.
//
// ws layout:
//   [0, 4096)      : W1 Phase-A A-fragments: 4 tiles x 64 lanes x 8 bf16.
//                    Lane l (neuron n = 32t + (l&31), h = l>>5):
//                      h=0, j<5: bf16hi(W1[n][j]); j==5: bf16hi(b1[n]); else 0
//                      h=1, j<5: bf16lo(W1[n][j]); j==5: bf16lo(b1[n]); else 0
//   [4096, 20480)  : W21/W22 GEMM2 A-fragments, frag F = mat*8 + kt (kt=2t+c):
//                    ushort idx F*512 + l*8 + j;
//                    value = W[n2 = l&31][k = 32t + 16c + 4*(l>>5) + (j&3) + 8*(j>>2)]
//
// Phase A: D_t = mfma_32x32x16(w1f[t], xb, 0) where xb carries {xh0..4, 1.0}
// in BOTH K-halves -> D = (W1hi+W1lo).xh + b1 (x rounded to bf16; same error
// order as the h1->bf16 pack that follows).
// The k-permutation above makes D_t's registers BE the GEMM2 B-fragment:
// au[2t+c][d] = pk(relu(D_t[8c+2d]), relu(D_t[8c+2d+1])). Zero shuffles.
// GEMM2 D2 = mfma(W2frag, au, acc): out-neuron i = (reg&3)+8*(reg>>2)+4h,
// batch row = lane&31. Heads: 16 lane-local FMAs + one shfl_xor(32).

__device__ __forceinline__ unsigned int rne_bf16_bits(float w) {
    unsigned int u = __builtin_bit_cast(unsigned int, w);
    u += 0x7fffu + ((u >> 16) & 1u);
    return u >> 16;
}
__device__ __forceinline__ float bf16_to_f32(unsigned int bits) {
    return __builtin_bit_cast(float, bits << 16);
}
__device__ __forceinline__ unsigned int pk_bf16(float lo, float hi) {
    __hip_bfloat162 bp = __float22bfloat162_rn(make_float2(lo, hi));
    unsigned int r; memcpy(&r, &bp, 4);
    return r;                                     // lo -> low 16, hi -> high 16
}

__global__ void setup_kernel(const float* __restrict__ W1, const float* __restrict__ b1,
                             const float* __restrict__ W21, const float* __restrict__ W22,
                             unsigned short* __restrict__ w1f, unsigned short* __restrict__ frg)
{
    int t = blockIdx.x * blockDim.x + threadIdx.x;   // 0..4095
    if (t < 2048) {  // W1 Phase-A table
        int e = t;
        int tt = e >> 9, l = (e >> 3) & 63, j = e & 7;
        int n = tt * 32 + (l & 31), h = l >> 5;
        unsigned short v = 0;
        float src = 0.0f; bool have = false;
        if (j < 5)       { src = W1[n * 5 + j]; have = true; }
        else if (j == 5) { src = b1[n];         have = true; }
        if (have) {
            unsigned int hi = rne_bf16_bits(src);
            if (h == 0) v = (unsigned short)hi;
            else        v = (unsigned short)rne_bf16_bits(src - bf16_to_f32(hi));
        }
        w1f[e] = v;
    }
    for (int e = t; e < 16 * 64 * 8; e += 4096) {    // GEMM2 table (8192 ushorts)
        int F = e >> 9, l = (e >> 3) & 63, j = e & 7;
        int mat = F >> 3, kt = F & 7;
        int tt = kt >> 1, c = kt & 1;
        int n2 = l & 31, h = l >> 5;
        int k = 32 * tt + 16 * c + 4 * h + (j & 3) + 8 * (j >> 2);
        const float* W = mat ? W22 : W21;
        frg[e] = (unsigned short)rne_bf16_bits(W[n2 * 128 + k]);
    }
}

// 512 blocks (2/CU resident -- R10 proved occupancy is not the limiter),
// block = 4 waves = 1024 rows; wave = 8 iters x 32 rows.
__global__ __launch_bounds__(BLK, 2) void barriernet_kernel(
    const float* __restrict__ x,
    const float* __restrict__ mean, const float* __restrict__ stdv,
    const float* __restrict__ b21, const float* __restrict__ b22,
    const float* __restrict__ W31, const float* __restrict__ b31,
    const float* __restrict__ W32, const float* __restrict__ b32,
    const u32x4* __restrict__ w1fg, const u32x4* __restrict__ frg,
    float* __restrict__ out, int zero)
{
    __shared__ u32x4 ldsF[1024];    // 16 GEMM2 frags x 64 lanes

    const int tid = threadIdx.x;
    #pragma unroll
    for (int i = 0; i < 4; ++i) ldsF[tid + i * BLK] = frg[tid + i * BLK];

    const int lane = tid & 63;
    const int wave = tid >> 6;
    const int R    = lane & 31;     // batch row within tile
    const int h    = lane >> 5;     // K-half / out-neuron offset bit

    // W1 Phase-A A-fragments: register-resident (16 VGPRs).
    u32x4 w1f[4];
    #pragma unroll
    for (int t = 0; t < 4; ++t) w1f[t] = w1fg[t * 64 + lane];

    // Bias / head vectors in out-neuron register order:
    // i = (reg&3) + 8*(reg>>2) + 4h  ->  quad rq: f32x4 at base + 8*rq + 4*h
    f32x4 bc21[4], bc22[4], wh31[4], wh32[4];
    #pragma unroll
    for (int rq = 0; rq < 4; ++rq) {
        bc21[rq] = *(const f32x4*)(b21 + 8 * rq + 4 * h);
        bc22[rq] = *(const f32x4*)(b22 + 8 * rq + 4 * h);
        wh31[rq] = *(const f32x4*)(W31 + 8 * rq + 4 * h);
        wh32[rq] = *(const f32x4*)(W32 + 8 * rq + 4 * h);
    }

    float sm_s[5], sm_m[5];
    #pragma unroll
    for (int f = 0; f < 5; ++f) { sm_s[f] = stdv[f]; sm_m[f] = mean[f]; }
    const float b31s = b31[0], b32s = b32[0];

    __syncthreads();

    const size_t wrow0 = (size_t)blockIdx.x * 1024 + wave * 256;

    // x prefetch for iter 0 (row wrow0 + R; 2x redundancy across halves)
    float4 xc4; float xc1;
    {
        const float* p = x + (wrow0 + R) * 5;
        xc4 = *(const float4*)p; xc1 = p[4];
    }

    #pragma unroll 1
    for (int it = 0; it < 8; ++it) {
        // ---- prefetch next iter's x ----
        const int itn = (it < 7) ? it + 1 : 7;
        const float* pn = x + (wrow0 + itn * 32 + R) * 5;
        float4 xn4 = *(const float4*)pn;
        float  xn1 = pn[4];

        const float xf[5] = { xc4.x, xc4.y, xc4.z, xc4.w, xc1 };

        // ---- Phase-A B-fragment: {bf16(x0..x4), 1.0, 0, 0} in both halves ----
        u32x4 xd;
        xd[0] = pk_bf16(xf[0], xf[1]);
        xd[1] = pk_bf16(xf[2], xf[3]);
        xd[2] = pk_bf16(xf[4], 1.0f);
        xd[3] = 0u;
        const bf16x8 xb = __builtin_bit_cast(bf16x8, xd);

        // ---- Phase A: 4 MFMAs (32x32x16); D_t regs ARE GEMM2 B-fragments ----
        unsigned int au[8][4];
        #pragma unroll
        for (int t = 0; t < 4; ++t) {
            f32x16 z = {};
            f32x16 D = __builtin_amdgcn_mfma_f32_32x32x16_bf16(
                __builtin_bit_cast(bf16x8, w1f[t]), xb, z, 0, 0, 0);
            #pragma unroll
            for (int c = 0; c < 2; ++c)
                #pragma unroll
                for (int d = 0; d < 4; ++d)
                    au[2 * t + c][d] = pk_bf16(fmaxf(D[8 * c + 2 * d],     0.0f),
                                               fmaxf(D[8 * c + 2 * d + 1], 0.0f));
        }

        // ---- GEMM2: 16 MFMAs (32x32x16), W2 A-frags from LDS ----
        f32x16 acc21, acc22;
        #pragma unroll
        for (int rq = 0; rq < 4; ++rq)
            #pragma unroll
            for (int r = 0; r < 4; ++r) {
                acc21[rq * 4 + r] = bc21[rq][r];
                acc22[rq * 4 + r] = bc22[rq][r];
            }
        const int fz = it * zero;                  // anti-hoist for LDS reads
        #pragma unroll
        for (int kt = 0; kt < 8; ++kt) {
            u32x4 t4 = { au[kt][0], au[kt][1], au[kt][2], au[kt][3] };
            const bf16x8 b = __builtin_bit_cast(bf16x8, t4);
            const bf16x8 wa21 = __builtin_bit_cast(bf16x8, ldsF[kt * 64 + lane + fz]);
            const bf16x8 wa22 = __builtin_bit_cast(bf16x8, ldsF[(8 + kt) * 64 + lane + fz]);
            acc21 = __builtin_amdgcn_mfma_f32_32x32x16_bf16(wa21, b, acc21, 0, 0, 0);
            acc22 = __builtin_amdgcn_mfma_f32_32x32x16_bf16(wa22, b, acc22, 0, 0, 0);
        }

        // ---- Heads: 16 lane-local FMAs each + one cross-half shuffle ----
        float s31 = 0.0f, s32 = 0.0f;
        #pragma unroll
        for (int rq = 0; rq < 4; ++rq)
            #pragma unroll
            for (int r = 0; r < 4; ++r) {
                s31 = fmaf(fmaxf(acc21[rq * 4 + r], 0.0f), wh31[rq][r], s31);
                s32 = fmaf(fmaxf(acc22[rq * 4 + r], 0.0f), wh32[rq][r], s32);
            }
        s31 += __shfl_xor(s31, 32);
        s32 += __shfl_xor(s32, 32);

        // ---- Epilogue (row R; lanes 0-31 store) ----
        const float x31 = s31 + b31s;
        const float z   = s32 + b32s;
        const float x32 = 4.0f / (1.0f + __expf(-z));
        float x0[5];
        #pragma unroll
        for (int f = 0; f < 5; ++f) x0[f] = fmaf(xf[f], sm_s[f], sm_m[f]);
        const float h_ineq = (x0[1] - x0[3]) + x32 * (x0[0] - x0[2] - 1.8f * x0[3]);
        const float u_unc  = -x31;
        const float u      = (1.8f * u_unc <= h_ineq) ? u_unc : (h_ineq / 1.8f);
        if (lane < 32)
            out[wrow0 + it * 32 + R] = u;

        xc4 = xn4; xc1 = xn1;
    }
}

extern "C" void kernel_launch(void* const* d_in, const int* in_sizes, int n_in,
                              void* d_out, int out_size, void* d_ws, size_t ws_size,
                              hipStream_t stream) {
    const float* x    = (const float*)d_in[0];
    const float* mean = (const float*)d_in[1];
    const float* stdv = (const float*)d_in[2];
    const float* W1   = (const float*)d_in[3];
    const float* b1   = (const float*)d_in[4];
    const float* W21  = (const float*)d_in[5];
    const float* b21  = (const float*)d_in[6];
    const float* W22  = (const float*)d_in[7];
    const float* b22  = (const float*)d_in[8];
    const float* W31  = (const float*)d_in[9];
    const float* b31  = (const float*)d_in[10];
    const float* W32  = (const float*)d_in[11];
    const float* b32  = (const float*)d_in[12];
    float* out = (float*)d_out;

    unsigned short* w1f = (unsigned short*)d_ws;
    unsigned short* frg = (unsigned short*)((char*)d_ws + 4096);

    setup_kernel<<<16, 256, 0, stream>>>(W1, b1, W21, W22, w1f, frg);

    // 524288 rows / 1024 rows-per-block = 512 blocks
    barriernet_kernel<<<512, BLK, 0, stream>>>(
        x, mean, stdv, b21, b22, W31, b31, W32, b32,
        (const u32x4*)w1f, (const u32x4*)frg, out, /*zero=*/0);
}